// Round 4
// baseline (167.463 us; speedup 1.0000x reference)
//
#include <hip/hip_runtime.h>
#include <hip/hip_bf16.h>

#define Bv 32
#define Dv 512
#define Kv 64
#define Nv 1024
#define EPSv 1e-12f

typedef __attribute__((ext_vector_type(8))) short bf16x8;
typedef __attribute__((ext_vector_type(4))) float f32x4;

// fp32 -> bf16 (RNE), bit-level
__device__ __forceinline__ unsigned short f2b(float f) {
  union { float f; unsigned u; } v; v.f = f;
  unsigned r = v.u + 0x7fffu + ((v.u >> 16) & 1u);
  return (unsigned short)(r >> 16);
}
__device__ __forceinline__ unsigned pack2(float a, float b) {
  return (unsigned)f2b(a) | ((unsigned)f2b(b) << 16);
}

// ---------------------------------------------------------------------------
// Kernel W: convert conv_w (K x D fp32) -> bf16. 32 blocks x 256 thr.
// ---------------------------------------------------------------------------
__global__ __launch_bounds__(256) void wconv(const float* __restrict__ w,
                                             unsigned short* __restrict__ wbf) {
  int i = (blockIdx.x * 256 + threadIdx.x) * 4;
  float4 v = *(const float4*)&w[i];
  uint2 o = make_uint2(pack2(v.x, v.y), pack2(v.z, v.w));
  *(uint2*)&wbf[i] = o;
}

// ---------------------------------------------------------------------------
// Kernel T: per 64d x 64n tile: read x fp32, write xbf[d][n] (direct) and
// xT[n][d] (via LDS transpose), both bf16. Grid (128, 32), 256 threads.
// ---------------------------------------------------------------------------
__global__ __launch_bounds__(256) void transpose_cvt(
    const float* __restrict__ x, unsigned short* __restrict__ xT,
    unsigned short* __restrict__ xbf) {
  __shared__ unsigned short xs[64 * 76];   // [d][n], pitch 76 shorts (152B)
  const int t = threadIdx.x;
  const int b = blockIdx.y;
  const int n0 = (blockIdx.x & 15) * 64;
  const int d0 = (blockIdx.x >> 4) * 64;

#pragma unroll
  for (int r = 0; r < 4; r++) {
    int d = r * 16 + (t >> 4);
    int n4 = (t & 15) * 4;
    float4 v = *(const float4*)&x[((size_t)b * Dv + d0 + d) * Nv + n0 + n4];
    uint2 p = make_uint2(pack2(v.x, v.y), pack2(v.z, v.w));
    *(uint2*)&xs[d * 76 + n4] = p;
    *(uint2*)&xbf[((size_t)b * Dv + d0 + d) * Nv + n0 + n4] = p;
  }
  __syncthreads();
#pragma unroll
  for (int r = 0; r < 4; r++) {
    int n = r * 16 + (t >> 4);
    int d4 = (t & 15) * 4;
    unsigned short s0 = xs[(d4 + 0) * 76 + n];
    unsigned short s1 = xs[(d4 + 1) * 76 + n];
    unsigned short s2 = xs[(d4 + 2) * 76 + n];
    unsigned short s3 = xs[(d4 + 3) * 76 + n];
    uint2 o = make_uint2((unsigned)s0 | ((unsigned)s1 << 16),
                         (unsigned)s2 | ((unsigned)s3 << 16));
    *(uint2*)&xT[((size_t)b * Nv + n0 + n) * Dv + d0 + d4] = o;
  }
}

// ---------------------------------------------------------------------------
// Kernel A: scores = conv_w @ x[b] (64k x 32n) via bf16 MFMA; all operands
// direct contiguous 16B bf16 loads (wbf rows, xT rows). Softmax over k
// in-block, write assign (bf16) + asum (fp32 atomics).
// Grid (N/32, B) = (32, 32), 256 threads.
// ---------------------------------------------------------------------------
__global__ __launch_bounds__(256) void score_softmax_assign(
    const unsigned short* __restrict__ xT, const unsigned short* __restrict__ wbf,
    unsigned short* __restrict__ assign, float* __restrict__ asum) {
  __shared__ float s[64 * 33];
  __shared__ float red[8][32];
  __shared__ float scol[32];

  const int t = threadIdx.x;
  const int b = blockIdx.y;
  const int n0 = blockIdx.x * 32;
  const int wv = t >> 6;
  const int lane = t & 63;
  const int q = lane >> 4;
  const int m = lane & 15;

  f32x4 acc0 = {0.f, 0.f, 0.f, 0.f};
  f32x4 acc1 = {0.f, 0.f, 0.f, 0.f};

  const unsigned short* wp = wbf + (size_t)(wv * 16 + m) * Dv + q * 8;
  const unsigned short* xp0 = xT + ((size_t)b * Nv + n0 + m) * Dv + q * 8;
  const unsigned short* xp1 = xp0 + (size_t)16 * Dv;

#pragma unroll 4
  for (int d0 = 0; d0 < Dv; d0 += 32) {
    bf16x8 af = *(const bf16x8*)(wp + d0);
    bf16x8 b0 = *(const bf16x8*)(xp0 + d0);
    bf16x8 b1 = *(const bf16x8*)(xp1 + d0);
    acc0 = __builtin_amdgcn_mfma_f32_16x16x32_bf16(af, b0, acc0, 0, 0, 0);
    acc1 = __builtin_amdgcn_mfma_f32_16x16x32_bf16(af, b1, acc1, 0, 0, 0);
  }

  // scores -> LDS: C/D layout col(n)=m, row(k)=q*4+r
#pragma unroll
  for (int r = 0; r < 4; r++) {
    s[(wv * 16 + q * 4 + r) * 33 + m] = acc0[r];
    s[(wv * 16 + q * 4 + r) * 33 + 16 + m] = acc1[r];
  }
  __syncthreads();

  // softmax over k (64) per column; 8 threads per column
  const int c = t & 31;
  const int g = t >> 5;
  float mx = -1e30f;
#pragma unroll
  for (int kk = 0; kk < 8; kk++) mx = fmaxf(mx, s[(g * 8 + kk) * 33 + c]);
  red[g][c] = mx;
  __syncthreads();
  float mcol = red[0][c];
#pragma unroll
  for (int i = 1; i < 8; i++) mcol = fmaxf(mcol, red[i][c]);
  float ps = 0.f;
#pragma unroll
  for (int kk = 0; kk < 8; kk++) {
    float e = __expf(s[(g * 8 + kk) * 33 + c] - mcol);
    s[(g * 8 + kk) * 33 + c] = e;
    ps += e;
  }
  __syncthreads();
  red[g][c] = ps;
  __syncthreads();
  float sum = red[0][c];
#pragma unroll
  for (int i = 1; i < 8; i++) sum += red[i][c];
  if (g == 0) scol[c] = 1.0f / sum;
  __syncthreads();

  if (t < 64) {
    float sk = 0.f;
#pragma unroll
    for (int c2 = 0; c2 < 32; c2++) sk += s[t * 33 + c2] * scol[c2];
    atomicAdd(&asum[b * Kv + t], sk);
  }

  unsigned short* ab = assign + (size_t)b * Kv * Nv + n0;
#pragma unroll
  for (int r2 = 0; r2 < 4; r2++) {
    int idx = r2 * 256 + t;
    int k = idx >> 4;
    int np = (idx & 15) * 2;
    unsigned pk = (unsigned)f2b(s[k * 33 + np] * scol[np]) |
                  ((unsigned)f2b(s[k * 33 + np + 1] * scol[np + 1]) << 16);
    *(unsigned*)&ab[(size_t)k * Nv + np] = pk;
  }
}

// ---------------------------------------------------------------------------
// Kernel B: vlad[b,d,k] = sum_n xbf*assign - centers*asum via bf16 MFMA.
// Pure load->MFMA loop (zero VALU); fuses colsq via shuffle + atomics.
// Grid (D/16, B) = (32, 32), 256 threads; wave wv owns k-cols [wv*16, +16).
// ---------------------------------------------------------------------------
__global__ __launch_bounds__(256) void vlad_mfma(
    const unsigned short* __restrict__ xbf, const unsigned short* __restrict__ assign,
    const float* __restrict__ centers, const float* __restrict__ asum,
    float* __restrict__ vlad, float* __restrict__ colsq) {
  const int t = threadIdx.x;
  const int b = blockIdx.y;
  const int d0 = blockIdx.x * 16;
  const int wv = t >> 6;
  const int lane = t & 63;
  const int q = lane >> 4;
  const int m = lane & 15;

  f32x4 acc0 = {0.f, 0.f, 0.f, 0.f};
  f32x4 acc1 = {0.f, 0.f, 0.f, 0.f};

  const unsigned short* xp = xbf + ((size_t)b * Dv + d0 + m) * Nv + q * 8;
  const unsigned short* ap = assign + ((size_t)b * Kv + wv * 16 + m) * Nv + q * 8;

#pragma unroll 8
  for (int n = 0; n < Nv; n += 64) {
    bf16x8 a0 = *(const bf16x8*)(xp + n);
    bf16x8 f0 = *(const bf16x8*)(ap + n);
    bf16x8 a1 = *(const bf16x8*)(xp + n + 32);
    bf16x8 f1 = *(const bf16x8*)(ap + n + 32);
    acc0 = __builtin_amdgcn_mfma_f32_16x16x32_bf16(a0, f0, acc0, 0, 0, 0);
    acc1 = __builtin_amdgcn_mfma_f32_16x16x32_bf16(a1, f1, acc1, 0, 0, 0);
  }

  const int k = wv * 16 + m;
  const float as = asum[b * Kv + k];
  float ss = 0.f;
#pragma unroll
  for (int r = 0; r < 4; r++) {
    int d = d0 + q * 4 + r;
    float v = (acc0[r] + acc1[r]) - centers[d * Kv + k] * as;
    vlad[((size_t)b * Dv + d) * Kv + k] = v;
    ss = fmaf(v, v, ss);
  }
  ss += __shfl_xor(ss, 16);
  ss += __shfl_xor(ss, 32);
  if (q == 0) atomicAdd(&colsq[b * Kv + k], ss);
}

// ---------------------------------------------------------------------------
// Kernel D: out = vlad * colscale[b,k] * bscale[b]; scales from colsq
// in-block. Grid 4096 x 256.
// ---------------------------------------------------------------------------
__global__ __launch_bounds__(256) void scale_kernel(
    const float* __restrict__ vlad, const float* __restrict__ colsq,
    float* __restrict__ out) {
  const int t = threadIdx.x;
  const size_t i = (size_t)blockIdx.x * 256 + t;
  const int b = (int)(i >> 15);  // D*K = 32768 per b
  __shared__ float scs[64];
  __shared__ float bsh;
  if (t < 64) {
    float tot = colsq[b * Kv + t];
    float sc = 1.0f / fmaxf(sqrtf(tot), EPSv);
    scs[t] = sc;
    float contrib = tot * sc * sc;
#pragma unroll
    for (int off = 32; off > 0; off >>= 1) contrib += __shfl_down(contrib, off);
    if (t == 0) bsh = 1.0f / fmaxf(sqrtf(contrib), EPSv);
  }
  __syncthreads();
  out[i] = vlad[i] * scs[i & 63] * bsh;
}

extern "C" void kernel_launch(void* const* d_in, const int* in_sizes, int n_in,
                              void* d_out, int out_size, void* d_ws, size_t ws_size,
                              hipStream_t stream) {
  const float* x = (const float*)d_in[0];        // [B, D, N]
  const float* w = (const float*)d_in[1];        // [K, D]
  const float* centers = (const float*)d_in[2];  // [D, K]
  float* out = (float*)d_out;                    // [B, D*K]

  char* ws = (char*)d_ws;
  unsigned short* xT = (unsigned short*)ws;                    // [B][N][D] bf16, 32 MB
  unsigned short* xbf = (unsigned short*)(ws + 33554432);      // [B][D][N] bf16, 32 MB
  unsigned short* assign = (unsigned short*)(ws + 67108864);   // [B][K][N] bf16, 4 MB
  float* vlad = (float*)(ws + 71303168);                       // [B][D][K] fp32, 4 MB
  unsigned short* wbf = (unsigned short*)(ws + 75497472);      // [K][D] bf16, 64 KB
  float* asum = (float*)(ws + 75563008);                       // B*K
  float* colsq = asum + Bv * Kv;                               // B*K

  hipMemsetAsync(asum, 0, (size_t)2 * Bv * Kv * sizeof(float), stream);

  wconv<<<32, 256, 0, stream>>>(w, wbf);
  transpose_cvt<<<dim3(128, Bv), 256, 0, stream>>>(x, xT, xbf);
  score_softmax_assign<<<dim3(Nv / 32, Bv), 256, 0, stream>>>(xT, wbf, assign, asum);
  vlad_mfma<<<dim3(Dv / 16, Bv), 256, 0, stream>>>(xbf, assign, centers, asum, vlad, colsq);
  scale_kernel<<<(Bv * Dv * Kv) / 256, 256, 0, stream>>>(vlad, colsq, out);
}

// Round 5
// 147.639 us; speedup vs baseline: 1.1343x; 1.1343x over previous
//
#include <hip/hip_runtime.h>
#include <hip/hip_bf16.h>

#define Bv 32
#define Dv 512
#define Kv 64
#define Nv 1024
#define EPSv 1e-12f

typedef __attribute__((ext_vector_type(8))) short bf16x8;
typedef __attribute__((ext_vector_type(4))) float f32x4;

// fp32 -> bf16 (RNE), bit-level
__device__ __forceinline__ unsigned short f2b(float f) {
  union { float f; unsigned u; } v; v.f = f;
  unsigned r = v.u + 0x7fffu + ((v.u >> 16) & 1u);
  return (unsigned short)(r >> 16);
}
__device__ __forceinline__ unsigned pack2(float a, float b) {
  return (unsigned)f2b(a) | ((unsigned)f2b(b) << 16);
}

// ---------------------------------------------------------------------------
// Kernel W: convert conv_w (K x D fp32) -> bf16. 32 blocks x 256 thr.
// ---------------------------------------------------------------------------
__global__ __launch_bounds__(256) void wconv(const float* __restrict__ w,
                                             unsigned short* __restrict__ wbf) {
  int i = (blockIdx.x * 256 + threadIdx.x) * 4;
  float4 v = *(const float4*)&w[i];
  uint2 o = make_uint2(pack2(v.x, v.y), pack2(v.z, v.w));
  *(uint2*)&wbf[i] = o;
}

// ---------------------------------------------------------------------------
// Kernel 1 (fused T+A): per (b, 64-n tile):
//  - stage x fp32 [512d x 64n] -> LDS xT[n][d] bf16 (pitch 520) + global xbf
//  - scores GEMM 64k x 64n via MFMA (A from wbf global/L2, B ds_read_b128)
//  - softmax over k via shuffle + 2 small LDS reductions
//  - write assign bf16 + asum atomics
// Grid (N/64, B) = (16, 32) = 512 blocks, 512 threads (8 waves).
// LDS ~68.6 KB -> 2 blocks/CU, 16 waves/CU.
// ---------------------------------------------------------------------------
__global__ __launch_bounds__(512) void fused_scores(
    const float* __restrict__ x, const unsigned short* __restrict__ wbf,
    unsigned short* __restrict__ xbf, unsigned short* __restrict__ assign,
    float* __restrict__ asum) {
  __shared__ unsigned short xT[64 * 520];   // [n][d], pitch 520 shorts (1040B, 16B-aligned)
  __shared__ float redmax[4][64];
  __shared__ float redsum[4][64];

  const int t = threadIdx.x;   // 0..511
  const int b = blockIdx.y;
  const int n0 = blockIdx.x * 64;

  // ---------------- staging ----------------
  {
    const int lo = t & 15;     // n-quad
    const int hi = t >> 4;     // 0..31 (d-pair subindex)
    const float* xb = x + (size_t)b * Dv * Nv + n0;
    unsigned short* xo = xbf + (size_t)b * Dv * Nv + n0;
#pragma unroll
    for (int r = 0; r < 8; r++) {
      int d = (hi + 32 * r) * 2;        // even d row; covers 0..510
      int n4 = lo * 4;
      float4 v0 = *(const float4*)&xb[(size_t)d * Nv + n4];
      float4 v1 = *(const float4*)&xb[(size_t)(d + 1) * Nv + n4];
      unsigned short a0 = f2b(v0.x), a1 = f2b(v0.y), a2 = f2b(v0.z), a3 = f2b(v0.w);
      unsigned short b0 = f2b(v1.x), b1 = f2b(v1.y), b2 = f2b(v1.z), b3 = f2b(v1.w);
      // global xbf rows d, d+1 (uint2 = 4 bf16 each, coalesced)
      *(uint2*)&xo[(size_t)d * Nv + n4] =
          make_uint2((unsigned)a0 | ((unsigned)a1 << 16), (unsigned)a2 | ((unsigned)a3 << 16));
      *(uint2*)&xo[(size_t)(d + 1) * Nv + n4] =
          make_uint2((unsigned)b0 | ((unsigned)b1 << 16), (unsigned)b2 | ((unsigned)b3 << 16));
      // LDS xT: dword at [n][d] = (x[d][n], x[d+1][n]); d even -> aligned
      *(unsigned*)&xT[(n4 + 0) * 520 + d] = (unsigned)a0 | ((unsigned)b0 << 16);
      *(unsigned*)&xT[(n4 + 1) * 520 + d] = (unsigned)a1 | ((unsigned)b1 << 16);
      *(unsigned*)&xT[(n4 + 2) * 520 + d] = (unsigned)a2 | ((unsigned)b2 << 16);
      *(unsigned*)&xT[(n4 + 3) * 520 + d] = (unsigned)a3 | ((unsigned)b3 << 16);
    }
  }
  __syncthreads();

  // ---------------- scores GEMM ----------------
  const int wv = t >> 6;        // 0..7
  const int lane = t & 63;
  const int q = lane >> 4;
  const int m = lane & 15;
  const int k16 = wv & 3;       // k-tile
  const int nsub = wv >> 2;     // n-half: cols [nsub*32, +32)

  f32x4 acc0 = {0.f, 0.f, 0.f, 0.f};
  f32x4 acc1 = {0.f, 0.f, 0.f, 0.f};

  const unsigned short* wp = wbf + (size_t)(k16 * 16 + m) * Dv + q * 8;
  const unsigned short* l0 = &xT[(nsub * 32 + m) * 520 + q * 8];
  const unsigned short* l1 = l0 + 16 * 520;

#pragma unroll
  for (int d0 = 0; d0 < Dv; d0 += 32) {
    bf16x8 af = *(const bf16x8*)(wp + d0);
    bf16x8 bf0 = *(const bf16x8*)(l0 + d0);
    bf16x8 bf1 = *(const bf16x8*)(l1 + d0);
    acc0 = __builtin_amdgcn_mfma_f32_16x16x32_bf16(af, bf0, acc0, 0, 0, 0);
    acc1 = __builtin_amdgcn_mfma_f32_16x16x32_bf16(af, bf1, acc1, 0, 0, 0);
  }

  // ---------------- softmax over k (64) ----------------
  // lane (q,m) holds rows k16*16 + q*4 + r, cols n0 + nsub*32 + {m, 16+m}
  float m0 = fmaxf(fmaxf(acc0[0], acc0[1]), fmaxf(acc0[2], acc0[3]));
  float m1 = fmaxf(fmaxf(acc1[0], acc1[1]), fmaxf(acc1[2], acc1[3]));
  m0 = fmaxf(m0, __shfl_xor(m0, 16)); m0 = fmaxf(m0, __shfl_xor(m0, 32));
  m1 = fmaxf(m1, __shfl_xor(m1, 16)); m1 = fmaxf(m1, __shfl_xor(m1, 32));
  if (q == 0) {
    redmax[k16][nsub * 32 + m] = m0;
    redmax[k16][nsub * 32 + 16 + m] = m1;
  }
  __syncthreads();
  const int c0 = nsub * 32 + m, c1 = c0 + 16;
  float mc0 = fmaxf(fmaxf(redmax[0][c0], redmax[1][c0]), fmaxf(redmax[2][c0], redmax[3][c0]));
  float mc1 = fmaxf(fmaxf(redmax[0][c1], redmax[1][c1]), fmaxf(redmax[2][c1], redmax[3][c1]));

  float e0[4], e1[4];
  float s0 = 0.f, s1 = 0.f;
#pragma unroll
  for (int r = 0; r < 4; r++) {
    e0[r] = __expf(acc0[r] - mc0); s0 += e0[r];
    e1[r] = __expf(acc1[r] - mc1); s1 += e1[r];
  }
  s0 += __shfl_xor(s0, 16); s0 += __shfl_xor(s0, 32);
  s1 += __shfl_xor(s1, 16); s1 += __shfl_xor(s1, 32);
  if (q == 0) {
    redsum[k16][c0] = s0;
    redsum[k16][c1] = s1;
  }
  __syncthreads();
  float sc0 = 1.0f / (redsum[0][c0] + redsum[1][c0] + redsum[2][c0] + redsum[3][c0]);
  float sc1 = 1.0f / (redsum[0][c1] + redsum[1][c1] + redsum[2][c1] + redsum[3][c1]);

  // ---------------- assign write + asum ----------------
  unsigned short* ab = assign + ((size_t)b * Kv + k16 * 16 + q * 4) * Nv + n0 + nsub * 32;
#pragma unroll
  for (int r = 0; r < 4; r++) {
    float v0 = e0[r] * sc0;
    float v1 = e1[r] * sc1;
    ab[(size_t)r * Nv + m] = f2b(v0);
    ab[(size_t)r * Nv + 16 + m] = f2b(v1);
    float p = v0 + v1;
    p += __shfl_xor(p, 1); p += __shfl_xor(p, 2);
    p += __shfl_xor(p, 4); p += __shfl_xor(p, 8);
    if (m == 0) atomicAdd(&asum[b * Kv + k16 * 16 + q * 4 + r], p);
  }
}

// ---------------------------------------------------------------------------
// Kernel 2: vlad[b,d,k] = sum_n xbf*assign - centers*asum via bf16 MFMA.
// n-contraction split across wave pairs (LDS reduce) -> 2048 blocks,
// 8 blocks/CU x 4 waves = 32 waves/CU (100% occupancy). Fuses colsq.
// Grid ((D/16)*(K/32), B) = (64, 32), 256 threads.
// ---------------------------------------------------------------------------
__global__ __launch_bounds__(256) void vlad_mfma(
    const unsigned short* __restrict__ xbf, const unsigned short* __restrict__ assign,
    const float* __restrict__ centers, const float* __restrict__ asum,
    float* __restrict__ vlad, float* __restrict__ colsq) {
  __shared__ float sred[2][64][4];   // [ksub][lane][r] from nh==1 waves

  const int t = threadIdx.x;
  const int b = blockIdx.y;
  const int gx = blockIdx.x;         // 0..63
  const int d0 = (gx >> 1) * 16;
  const int kb = (gx & 1) * 32;
  const int wv = t >> 6;
  const int ksub = wv & 1;
  const int nh = wv >> 1;            // n-half
  const int lane = t & 63;
  const int q = lane >> 4;
  const int m = lane & 15;
  const int k16 = kb + ksub * 16;

  f32x4 acc0 = {0.f, 0.f, 0.f, 0.f};
  f32x4 acc1 = {0.f, 0.f, 0.f, 0.f};

  const unsigned short* xp = xbf + ((size_t)b * Dv + d0 + m) * Nv + nh * 512 + q * 8;
  const unsigned short* ap = assign + ((size_t)b * Kv + k16 + m) * Nv + nh * 512 + q * 8;

#pragma unroll
  for (int n = 0; n < 512; n += 64) {
    bf16x8 a0 = *(const bf16x8*)(xp + n);
    bf16x8 f0 = *(const bf16x8*)(ap + n);
    bf16x8 a1 = *(const bf16x8*)(xp + n + 32);
    bf16x8 f1 = *(const bf16x8*)(ap + n + 32);
    acc0 = __builtin_amdgcn_mfma_f32_16x16x32_bf16(a0, f0, acc0, 0, 0, 0);
    acc1 = __builtin_amdgcn_mfma_f32_16x16x32_bf16(a1, f1, acc1, 0, 0, 0);
  }

  f32x4 v;
#pragma unroll
  for (int r = 0; r < 4; r++) v[r] = acc0[r] + acc1[r];

  if (nh == 1) {
#pragma unroll
    for (int r = 0; r < 4; r++) sred[ksub][lane][r] = v[r];
  }
  __syncthreads();
  if (nh == 0) {
    const int k = k16 + m;
    const float as = asum[b * Kv + k];
    float ss = 0.f;
#pragma unroll
    for (int r = 0; r < 4; r++) {
      v[r] += sred[ksub][lane][r];
      int d = d0 + q * 4 + r;
      float val = v[r] - centers[d * Kv + k] * as;
      vlad[((size_t)b * Dv + d) * Kv + k] = val;
      ss = fmaf(val, val, ss);
    }
    ss += __shfl_xor(ss, 16);
    ss += __shfl_xor(ss, 32);
    if (q == 0) atomicAdd(&colsq[b * Kv + k], ss);
  }
}

// ---------------------------------------------------------------------------
// Kernel D: out = vlad * colscale[b,k] * bscale[b]; scales from colsq
// in-block. Grid 4096 x 256.
// ---------------------------------------------------------------------------
__global__ __launch_bounds__(256) void scale_kernel(
    const float* __restrict__ vlad, const float* __restrict__ colsq,
    float* __restrict__ out) {
  const int t = threadIdx.x;
  const size_t i = (size_t)blockIdx.x * 256 + t;
  const int b = (int)(i >> 15);  // D*K = 32768 per b
  __shared__ float scs[64];
  __shared__ float bsh;
  if (t < 64) {
    float tot = colsq[b * Kv + t];
    float sc = 1.0f / fmaxf(sqrtf(tot), EPSv);
    scs[t] = sc;
    float contrib = tot * sc * sc;
#pragma unroll
    for (int off = 32; off > 0; off >>= 1) contrib += __shfl_down(contrib, off);
    if (t == 0) bsh = 1.0f / fmaxf(sqrtf(contrib), EPSv);
  }
  __syncthreads();
  out[i] = vlad[i] * scs[i & 63] * bsh;
}

extern "C" void kernel_launch(void* const* d_in, const int* in_sizes, int n_in,
                              void* d_out, int out_size, void* d_ws, size_t ws_size,
                              hipStream_t stream) {
  const float* x = (const float*)d_in[0];        // [B, D, N]
  const float* w = (const float*)d_in[1];        // [K, D]
  const float* centers = (const float*)d_in[2];  // [D, K]
  float* out = (float*)d_out;                    // [B, D*K]

  char* ws = (char*)d_ws;
  unsigned short* xbf = (unsigned short*)ws;                   // [B][D][N] bf16, 32 MB
  unsigned short* assign = (unsigned short*)(ws + 33554432);   // [B][K][N] bf16, 4 MB
  float* vlad = (float*)(ws + 37748736);                       // [B][D][K] fp32, 4 MB
  unsigned short* wbf = (unsigned short*)(ws + 41943040);      // [K][D] bf16, 64 KB
  float* asum = (float*)(ws + 42008576);                       // B*K
  float* colsq = asum + Bv * Kv;                               // B*K

  hipMemsetAsync(asum, 0, (size_t)2 * Bv * Kv * sizeof(float), stream);

  wconv<<<32, 256, 0, stream>>>(w, wbf);
  fused_scores<<<dim3(Nv / 64, Bv), 512, 0, stream>>>(x, wbf, xbf, assign, asum);
  vlad_mfma<<<dim3(64, Bv), 256, 0, stream>>>(xbf, assign, centers, asum, vlad, colsq);
  scale_kernel<<<(Bv * Dv * Kv) / 256, 256, 0, stream>>>(vlad, colsq, out);
}